// Round 18
// baseline (1355.485 us; speedup 1.0000x reference)
//
#include <hip/hip_runtime.h>
#include <math.h>

// Problem constants (N=2, C=64, H=96, W=96, PATCH=3)
static constexpr int NITEM = 2;
static constexpr int C = 64;
static constexpr int H = 96;
static constexpr int W = 96;
static constexpr int HW = H * W;         // 9216 pixels
static constexpr int HP = 94;            // H - 3 + 1
static constexpr int NP = HP * HP;       // 8836 patch positions

// ---- factored-path constants ----
// Band ladder is L3-constrained: pass2 re-reads each P element 9x, so the band
// slab must stay Infinity-Cache-resident. BRY18 = 142 MB (L3-resident, proven);
// BRY24 = 184 MB (R17: pass2 FETCH 254 MB/dispatch -> HBM-bound, net zero);
// BRY47 = 347 MB thrashed L3 and regressed (R13).
static constexpr int BRY_L  = 18;                   // 6 bands, PROWS=1920 (15x128 exact)
static constexpr int BRY_S  = 8;                    // 12 bands, PROWS=960 (fallback)
static constexpr int TSQ = 128;                     // q-tile edge
static constexpr int TN  = 256;                     // p-tile edge (8x16 per thread)
static constexpr int NPT = HW / TN;                 // 36 p-tiles (exact)
static constexpr int KC2 = 32;                      // K per staging round (2 rounds)
static constexpr int PADA = 132;                    // Aq row pad
static constexpr int PADB = 260;                    // Bp row pad
static constexpr int ITILE = 256;                   // i's per pass2 block
static constexpr int NIT = (NP + ITILE - 1) / ITILE; // 35

// ---- fallback (R4 direct) constants ----
static constexpr int NSEG = 8;
static constexpr int SEGLEN = (NP + NSEG - 1) / NSEG; // 1105
static constexpr int MT = 128;
static constexpr int NT = 128;
static constexpr int KC = 16;
static constexpr int LDP = MT + 4;
static constexpr int NMTILE = (NP + MT - 1) / MT;   // 70

// Order-preserving fp32 -> uint32 (v1 > v2  <=>  key(v1) > key(v2))
__device__ __forceinline__ unsigned int fkey(float v) {
    unsigned int u = __float_as_uint(v);
    return (u & 0x80000000u) ? ~u : (u | 0x80000000u);
}

// ---------------- Kernel 1: per-pixel channel L2 normalize + NCHW->NHWC ----------------
__global__ __launch_bounds__(256) void normalize_kernel(
    const float* __restrict__ f1, const float* __restrict__ f2,
    float* __restrict__ fiN, float* __restrict__ frN, float* __restrict__ ssn)
{
    int t = blockIdx.x * 256 + threadIdx.x;
    const int perTensor = NITEM * HW;
    if (t >= 2 * perTensor) return;
    int which = t / perTensor;
    int p = t - which * perTensor;
    int n = p / HW;
    int pix = p - n * HW;
    const float* src = (which ? f2 : f1) + (size_t)n * C * HW + pix;
    float s = 0.f;
    #pragma unroll
    for (int c = 0; c < C; c++) {
        float v = src[c * HW];
        s = fmaf(v, v, s);
    }
    float norm = sqrtf(s);
    float scale = 1.0f / fmaxf(norm, 1e-12f);
    float* dst = (which ? frN : fiN) + (size_t)p * C;
    #pragma unroll
    for (int c = 0; c < C; c++) {
        dst[c] = src[c * HW] * scale;
    }
    if (which) ssn[p] = s * scale * scale;
}

// ---------------- Kernel 2: ref patch inverse norms ----------------
__global__ __launch_bounds__(256) void refnorm_kernel(
    const float* __restrict__ ssn, float* __restrict__ invn)
{
    int t = blockIdx.x * 256 + threadIdx.x;
    if (t >= NITEM * NP) return;
    int n = t / NP;
    int r = t - n * NP;
    int yr = r / HP, xr = r - yr * HP;
    const float* s = ssn + n * HW;
    float acc = 0.f;
    #pragma unroll
    for (int dy = 0; dy < 3; dy++)
        #pragma unroll
        for (int dx = 0; dx < 3; dx++)
            acc += s[(yr + dy) * W + (xr + dx)];
    invn[t] = 1.0f / (sqrtf(acc) + 1e-5f);
}

// ================= FACTORED PATH =================
// Kernel A: GEMM writing RAW pixel-corr P[q][p]; 128q x 256p tile, 8x16/thread.
// LDS-issue model: 8x8 tile = 4 b128 / 64 FMA -> 67% ceiling (measured ~50%);
// 8x16 = 6 b128 / 128 FMA -> 89% ceiling. K staged in 2 rounds of 32 (50.2 KB
// LDS -> ~3 blocks/CU); k-order 0..63 unchanged -> bit-identical P.
__global__ __launch_bounds__(256) void gemmP_kernel(
    const float* __restrict__ fiN, const float* __restrict__ frN,
    float* __restrict__ pmat, int ry0, int prows)
{
    __shared__ struct { float Aq[KC2][PADA]; float Bp[KC2][PADB]; } sm;  // 50.2 KB

    const int t = threadIdx.x;
    const int pt0 = blockIdx.x * TN;     // input-pixel col base (256-aligned)
    const int qt0 = blockIdx.y * TSQ;    // P-local q base (128-aligned)
    const int n = blockIdx.z;

    const float* fa = frN + (size_t)n * HW * C;  // q side (ref)
    const float* fb = fiN + (size_t)n * HW * C;  // p side (input)

    const int tq = (t >> 4) * 8;    // q fragment base (0..120)
    const int tp = (t & 15) * 16;   // p fragment base (0..240)

    float acc[8][16];
    #pragma unroll
    for (int i = 0; i < 8; i++)
        #pragma unroll
        for (int j = 0; j < 16; j++) acc[i][j] = 0.f;

    // staging indices (round-invariant)
    int bpix = pt0 + t; if (bpix > HW - 1) bpix = HW - 1;            // Bp: 1 pixel/thread
    int arow = t >> 1;                                               // Aq: rows 0..127
    const int ach0 = (t & 1) * 16;                                   // ch half
    int apix = ry0 * W + qt0 + arow; if (apix > HW - 1) apix = HW - 1;

    #pragma unroll 1
    for (int kb = 0; kb < C; kb += KC2) {
        if (kb) __syncthreads();   // previous round's LDS reads complete
        {
            const float* pb = fb + (size_t)bpix * C + kb;
            #pragma unroll
            for (int u = 0; u < 8; u++) {
                float4 v = *(const float4*)(pb + 4 * u);
                sm.Bp[4 * u + 0][t] = v.x; sm.Bp[4 * u + 1][t] = v.y;
                sm.Bp[4 * u + 2][t] = v.z; sm.Bp[4 * u + 3][t] = v.w;
            }
            const float* qa = fa + (size_t)apix * C + kb + ach0;
            #pragma unroll
            for (int u = 0; u < 4; u++) {
                float4 v = *(const float4*)(qa + 4 * u);
                int cc = ach0 + 4 * u;
                sm.Aq[cc + 0][arow] = v.x; sm.Aq[cc + 1][arow] = v.y;
                sm.Aq[cc + 2][arow] = v.z; sm.Aq[cc + 3][arow] = v.w;
            }
        }
        __syncthreads();

        #pragma unroll 2
        for (int k = 0; k < KC2; k++) {
            float4 af0 = *(const float4*)&sm.Aq[k][tq];
            float4 af1 = *(const float4*)&sm.Aq[k][tq + 4];
            float4 bf0 = *(const float4*)&sm.Bp[k][tp];
            float4 bf1 = *(const float4*)&sm.Bp[k][tp + 4];
            float4 bf2 = *(const float4*)&sm.Bp[k][tp + 8];
            float4 bf3 = *(const float4*)&sm.Bp[k][tp + 12];
            float av[8] = {af0.x, af0.y, af0.z, af0.w, af1.x, af1.y, af1.z, af1.w};
            float bw[16] = {bf0.x, bf0.y, bf0.z, bf0.w, bf1.x, bf1.y, bf1.z, bf1.w,
                            bf2.x, bf2.y, bf2.z, bf2.w, bf3.x, bf3.y, bf3.z, bf3.w};
            #pragma unroll
            for (int i = 0; i < 8; i++)
                #pragma unroll
                for (int j = 0; j < 16; j++)
                    acc[i][j] = fmaf(av[i], bw[j], acc[i][j]);
        }
    }

    // ---- direct register->global stores (four float4 per q-row), fully coalesced
    float* pn = pmat + (size_t)n * prows * HW;
    #pragma unroll
    for (int i = 0; i < 8; i++) {
        int qL = qt0 + tq + i;
        if (qL < prows) {
            float* row = pn + (size_t)qL * HW + pt0 + tp;
            *(float4*)(row + 0)  = make_float4(acc[i][0],  acc[i][1],  acc[i][2],  acc[i][3]);
            *(float4*)(row + 4)  = make_float4(acc[i][4],  acc[i][5],  acc[i][6],  acc[i][7]);
            *(float4*)(row + 8)  = make_float4(acc[i][8],  acc[i][9],  acc[i][10], acc[i][11]);
            *(float4*)(row + 12) = make_float4(acc[i][12], acc[i][13], acc[i][14], acc[i][15]);
        }
    }
}

// Kernel B (R12-proven scalar form + atomic merge): 3x3 diagonal sum + norm
// scale + per-ry argmax, merged globally via packed-u64 atomicMax.
// key = (fkey(v) << 32) | ~idx  ->  max key == (max v, tie -> min idx).
// term(dy,dx) = P[(ryL+dy)*W + rx + dx][ppix + dy*W + dx] -> offset rx*HW + dx*(HW+1).
__global__ __launch_bounds__(256) void pass2_kernel(
    const float* __restrict__ pmat, const float* __restrict__ invn,
    unsigned long long* __restrict__ best, int ry0, int prows)
{
    const int t = threadIdx.x;
    const int ryL = blockIdx.x;          // P-local ref patch-row
    const int ry = ry0 + ryL;            // global ref patch-row
    const int n = blockIdx.z;
    const int i = blockIdx.y * ITILE + t;
    if (i >= NP) return;

    const float* pn = pmat + (size_t)n * prows * HW;
    const float* inv = invn + (size_t)n * NP + ry * HP;
    const int rBase = ry * HP;

    int iy = i / HP, ix = i - iy * HP;
    int ppix = iy * W + ix;
    const float* b0 = pn + (size_t)(ryL * W) * HW + ppix;
    const float* b1 = b0 + (size_t)W * HW + W;
    const float* b2 = b1 + (size_t)W * HW + W;
    const size_t D = (size_t)HW + 1;     // diagonal stride (+1 row, +1 col)

    float bv = -INFINITY;
    int brx = 0;
    #pragma unroll 4
    for (int rx = 0; rx < HP; rx++) {
        size_t o = (size_t)rx * HW;
        float s0 = (b0[o] + b0[o + D]) + b0[o + 2 * D];
        float s1 = (b1[o] + b1[o + D]) + b1[o + 2 * D];
        float s2 = (b2[o] + b2[o + D]) + b2[o + 2 * D];
        float v = ((s0 + s1) + s2) * inv[rx];
        if (v > bv) { bv = v; brx = rx; }
    }
    unsigned long long key = ((unsigned long long)fkey(bv) << 32)
                           | (unsigned int)(~(unsigned int)(rBase + brx));
    atomicMax(&best[(size_t)n * NP + i], key);
}

// Expand to 9 shifted copies, channel-interleaved; decodes best[] inline.
__global__ __launch_bounds__(256) void expand_best_kernel(
    const unsigned long long* __restrict__ best, float* __restrict__ out)
{
    int t = blockIdx.x * 256 + threadIdx.x;
    const int total = NITEM * 18 * HW;
    if (t >= total) return;
    int x = t % W;
    int y = (t / W) % H;
    int chn = (t / HW) % 18;
    int n = t / (18 * HW);
    int k = chn >> 1;
    int b = chn & 1;          // 0 -> flow_h, 1 -> flow_w
    int is = k / 3, js = k - is * 3;
    int ys = y - is, xs = x - js;
    float val = 0.f;
    if (ys >= 0 && ys < HP && xs >= 0 && xs < HP) {
        int i = ys * HP + xs;
        unsigned long long key = best[(size_t)n * NP + i];
        int idx = (int)(~(unsigned int)key);
        int yr = idx / HP, xr = idx - yr * HP;
        val = b ? (float)(xr - xs) : (float)(yr - ys);
    }
    out[t] = val;
}

// ================= FALLBACK PATH (R4 direct, proven) =================
__global__ __launch_bounds__(256) void corr_kernel(
    const float* __restrict__ fiN, const float* __restrict__ frN,
    const float* __restrict__ invn,
    float* __restrict__ bestv, int* __restrict__ besti)
{
    __shared__ union SM {
        struct { float A[KC][LDP]; float B[KC][LDP]; } g;
        struct { float rv[MT][16]; int ri[MT][16]; } red;
    } sm;

    const int t = threadIdx.x;
    const int itile = blockIdx.x;
    const int seg = blockIdx.y;
    const int n = blockIdx.z;

    const float* fa = fiN + (size_t)n * HW * C;
    const float* fb = frN + (size_t)n * HW * C;
    const float* inv = invn + (size_t)n * NP;

    const int lrow = t >> 2;
    const int lc = (t & 3) * 4;

    int ia0 = itile * MT + lrow;      if (ia0 > NP - 1) ia0 = NP - 1;
    int ia1 = itile * MT + lrow + 64; if (ia1 > NP - 1) ia1 = NP - 1;
    const int ay0 = ia0 / HP, ax0 = ia0 - ay0 * HP;
    const int ay1 = ia1 / HP, ax1 = ia1 - ay1 * HP;
    const int aoff0 = (ay0 * W + ax0) * C;
    const int aoff1 = (ay1 * W + ax1) * C;

    const int tm4 = (t & 15) * 4;
    const int tn4 = (t >> 4) * 4;

    const int segStart = seg * SEGLEN;
    const int segEnd = (segStart + SEGLEN < NP) ? segStart + SEGLEN : NP;

    float bv[8];
    int bi[8];
    #pragma unroll
    for (int i = 0; i < 8; i++) { bv[i] = -INFINITY; bi[i] = 0; }

    for (int rt = segStart; rt < segEnd; rt += NT) {
        int ib0 = rt + lrow;      if (ib0 > NP - 1) ib0 = NP - 1;
        int ib1 = rt + lrow + 64; if (ib1 > NP - 1) ib1 = NP - 1;
        const int by0 = ib0 / HP, bx0 = ib0 - by0 * HP;
        const int by1 = ib1 / HP, bx1 = ib1 - by1 * HP;
        const int boff0 = (by0 * W + bx0) * C;
        const int boff1 = (by1 * W + bx1) * C;

        float acc[8][8];
        #pragma unroll
        for (int i = 0; i < 8; i++)
            #pragma unroll
            for (int j = 0; j < 8; j++) acc[i][j] = 0.f;

        float4 a0 = *(const float4*)(fa + aoff0 + lc);
        float4 a1 = *(const float4*)(fa + aoff1 + lc);
        float4 b0 = *(const float4*)(fb + boff0 + lc);
        float4 b1 = *(const float4*)(fb + boff1 + lc);

        #pragma unroll 1
        for (int ch = 0; ch < 36; ch++) {
            __syncthreads();
            sm.g.A[lc + 0][lrow] = a0.x; sm.g.A[lc + 1][lrow] = a0.y;
            sm.g.A[lc + 2][lrow] = a0.z; sm.g.A[lc + 3][lrow] = a0.w;
            sm.g.A[lc + 0][lrow + 64] = a1.x; sm.g.A[lc + 1][lrow + 64] = a1.y;
            sm.g.A[lc + 2][lrow + 64] = a1.z; sm.g.A[lc + 3][lrow + 64] = a1.w;
            sm.g.B[lc + 0][lrow] = b0.x; sm.g.B[lc + 1][lrow] = b0.y;
            sm.g.B[lc + 2][lrow] = b0.z; sm.g.B[lc + 3][lrow] = b0.w;
            sm.g.B[lc + 0][lrow + 64] = b1.x; sm.g.B[lc + 1][lrow + 64] = b1.y;
            sm.g.B[lc + 2][lrow + 64] = b1.z; sm.g.B[lc + 3][lrow + 64] = b1.w;
            __syncthreads();

            if (ch < 35) {
                const int chn = ch + 1;
                const int pp = chn >> 2;
                const int c0 = (chn & 3) << 4;
                const int dy = pp / 3, dx = pp - dy * 3;
                const int poff = (dy * W + dx) * C + c0 + lc;
                a0 = *(const float4*)(fa + aoff0 + poff);
                a1 = *(const float4*)(fa + aoff1 + poff);
                b0 = *(const float4*)(fb + boff0 + poff);
                b1 = *(const float4*)(fb + boff1 + poff);
            }

            #pragma unroll
            for (int k = 0; k < KC; k++) {
                float4 af0 = *(const float4*)&sm.g.A[k][tm4];
                float4 af1 = *(const float4*)&sm.g.A[k][tm4 + 64];
                float4 bf0 = *(const float4*)&sm.g.B[k][tn4];
                float4 bf1 = *(const float4*)&sm.g.B[k][tn4 + 64];
                float av[8] = {af0.x, af0.y, af0.z, af0.w, af1.x, af1.y, af1.z, af1.w};
                float bw[8] = {bf0.x, bf0.y, bf0.z, bf0.w, bf1.x, bf1.y, bf1.z, bf1.w};
                #pragma unroll
                for (int i = 0; i < 8; i++)
                    #pragma unroll
                    for (int j = 0; j < 8; j++)
                        acc[i][j] = fmaf(av[i], bw[j], acc[i][j]);
            }
        }

        #pragma unroll
        for (int j = 0; j < 8; j++) {
            int col = tn4 + ((j < 4) ? j : 60 + j);
            int r = rt + col;
            bool valid = (r < segEnd);
            float iv = inv[valid ? r : 0];
            #pragma unroll
            for (int i = 0; i < 8; i++) {
                float v = acc[i][j] * iv;
                if (valid && v > bv[i]) { bv[i] = v; bi[i] = r; }
            }
        }
    }

    __syncthreads();
    #pragma unroll
    for (int i = 0; i < 8; i++) {
        int row = tm4 + ((i < 4) ? i : 60 + i);
        sm.red.rv[row][t >> 4] = bv[i];
        sm.red.ri[row][t >> 4] = bi[i];
    }
    __syncthreads();
    if (t < MT) {
        float v = sm.red.rv[t][0];
        int idx = sm.red.ri[t][0];
        #pragma unroll
        for (int j = 1; j < 16; j++) {
            float v2 = sm.red.rv[t][j];
            int i2 = sm.red.ri[t][j];
            if (v2 > v || (v2 == v && i2 < idx)) { v = v2; idx = i2; }
        }
        int gi = itile * MT + t;
        if (gi < NP) {
            size_t o = ((size_t)n * NSEG + seg) * NP + gi;
            bestv[o] = v;
            besti[o] = idx;
        }
    }
}

__global__ __launch_bounds__(256) void reduce_flow_kernel(
    const float* __restrict__ bestv, const int* __restrict__ besti,
    float* __restrict__ flowh, float* __restrict__ floww)
{
    int t = blockIdx.x * 256 + threadIdx.x;
    if (t >= NITEM * NP) return;
    int n = t / NP;
    int i = t - n * NP;
    const float* bvp = bestv + (size_t)n * NSEG * NP;
    const int* bip = besti + (size_t)n * NSEG * NP;
    float v = bvp[i];
    int idx = bip[i];
    #pragma unroll
    for (int s = 1; s < NSEG; s++) {
        float v2 = bvp[s * NP + i];
        int i2 = bip[s * NP + i];
        if (v2 > v || (v2 == v && i2 < idx)) { v = v2; idx = i2; }
    }
    int yi = i / HP, xi = i - yi * HP;
    int yr = idx / HP, xr = idx - yr * HP;
    flowh[t] = (float)(yr - yi);
    floww[t] = (float)(xr - xi);
}

__global__ __launch_bounds__(256) void expand_kernel(
    const float* __restrict__ flowh, const float* __restrict__ floww,
    float* __restrict__ out)
{
    int t = blockIdx.x * 256 + threadIdx.x;
    const int total = NITEM * 18 * HW;
    if (t >= total) return;
    int x = t % W;
    int y = (t / W) % H;
    int chn = (t / HW) % 18;
    int n = t / (18 * HW);
    int k = chn >> 1;
    int b = chn & 1;
    int is = k / 3, js = k - is * 3;
    int ys = y - is, xs = x - js;
    float val = 0.f;
    if (ys >= 0 && ys < HP && xs >= 0 && xs < HP) {
        int src = n * NP + ys * HP + xs;
        val = b ? floww[src] : flowh[src];
    }
    out[t] = val;
}

// ---------------- Launch ----------------
extern "C" void kernel_launch(void* const* d_in, const int* in_sizes, int n_in,
                              void* d_out, int out_size, void* d_ws, size_t ws_size,
                              hipStream_t stream) {
    (void)in_sizes; (void)n_in; (void)out_size;
    const float* f1 = (const float*)d_in[0];
    const float* f2 = (const float*)d_in[1];
    float* ws = (float*)d_ws;

    // common carve
    float* fiN  = ws;                                  // 2*9216*64
    float* frN  = fiN + NITEM * HW * C;                // 2*9216*64
    float* ssn  = frN + NITEM * HW * C;                // 2*9216
    float* invn = ssn + NITEM * HW;                    // 2*8836
    float* after = invn + NITEM * NP;
    size_t afterOff = ((size_t)(after - ws) + 63) & ~(size_t)63;

    float* pmat = ws + afterOff;
    auto tier_fits = [&](int bry) {
        size_t prowsT = (size_t)(bry + 2) * W;
        size_t words = afterOff + (size_t)NITEM * prowsT * HW
                     + (size_t)NITEM * NP * 2 /* u64 best */;
        return ws_size >= words * sizeof(float);
    };

    int bry = 0;
    if (tier_fits(BRY_L)) bry = BRY_L;          // L3-resident band (proven best)
    else if (tier_fits(BRY_S)) bry = BRY_S;

    {
        int nthreads = 2 * NITEM * HW;
        normalize_kernel<<<(nthreads + 255) / 256, 256, 0, stream>>>(f1, f2, fiN, frN, ssn);
    }
    {
        int nthreads = NITEM * NP;
        refnorm_kernel<<<(nthreads + 255) / 256, 256, 0, stream>>>(ssn, invn);
    }

    if (bry > 0) {
        size_t prowsT = (size_t)(bry + 2) * W;
        unsigned long long* best =
            (unsigned long long*)(pmat + (size_t)NITEM * prowsT * HW);
        hipMemsetAsync(best, 0, (size_t)NITEM * NP * sizeof(unsigned long long), stream);

        for (int ry0 = 0; ry0 < HP; ry0 += bry) {
            int bryb = (HP - ry0 < bry) ? (HP - ry0) : bry;
            int prows_used = (bryb + 2) * W;
            int nqt = (prows_used + TSQ - 1) / TSQ;
            dim3 ga(NPT, nqt, NITEM);
            gemmP_kernel<<<ga, 256, 0, stream>>>(fiN, frN, pmat, ry0, prows_used);
            dim3 gb(bryb, NIT, NITEM);
            pass2_kernel<<<gb, 256, 0, stream>>>(pmat, invn, best, ry0, prows_used);
        }
        expand_best_kernel<<<(NITEM * 18 * HW + 255) / 256, 256, 0, stream>>>(
            best, (float*)d_out);
    } else {
        // direct fallback carve (fits ~10 MB)
        float* bestv = ws + afterOff;                       // 2*8*8836
        int*   besti = (int*)(bestv + NITEM * NSEG * NP);
        float* flowh = (float*)(besti + NITEM * NSEG * NP);
        float* floww = flowh + NITEM * NP;
        dim3 grid(NMTILE, NSEG, NITEM);
        corr_kernel<<<grid, 256, 0, stream>>>(fiN, frN, invn, bestv, besti);
        int nthreads = NITEM * NP;
        reduce_flow_kernel<<<(nthreads + 255) / 256, 256, 0, stream>>>(bestv, besti, flowh, floww);
        expand_kernel<<<(NITEM * 18 * HW + 255) / 256, 256, 0, stream>>>(flowh, floww, (float*)d_out);
    }
}

// Round 19
// 817.404 us; speedup vs baseline: 1.6583x; 1.6583x over previous
//
#include <hip/hip_runtime.h>
#include <math.h>

// Problem constants (N=2, C=64, H=96, W=96, PATCH=3)
static constexpr int NITEM = 2;
static constexpr int C = 64;
static constexpr int H = 96;
static constexpr int W = 96;
static constexpr int HW = H * W;         // 9216 pixels
static constexpr int HP = 94;            // H - 3 + 1
static constexpr int NP = HP * HP;       // 8836 patch positions

// ---- factored-path constants ----
// BRY18 = 142 MB band slab: L3-resident (proven R12/R16). Bigger bands lose
// pass2's L3 residency (R13/R17 measured).
static constexpr int BRY_L  = 18;                   // 6 bands, PROWS=1920 (15x128 exact)
static constexpr int BRY_S  = 8;                    // 12 bands, PROWS=960 (fallback)
static constexpr int TSQ = 128;                     // q-tile edge
static constexpr int TN  = 256;                     // p-tile edge (8x16 per thread)
static constexpr int NPT = HW / TN;                 // 36 p-tiles (exact)
static constexpr int KC2 = 32;                      // K per staging round (2 rounds)
static constexpr int PADA = 132;                    // Aq row pad
static constexpr int PADB = 260;                    // Bp row pad
static constexpr int ITILE = 256;                   // i's per pass2 block
static constexpr int NIT = (NP + ITILE - 1) / ITILE; // 35

// ---- fallback (R4 direct) constants ----
static constexpr int NSEG = 8;
static constexpr int SEGLEN = (NP + NSEG - 1) / NSEG; // 1105
static constexpr int MT = 128;
static constexpr int NT = 128;
static constexpr int KC = 16;
static constexpr int LDP = MT + 4;
static constexpr int NMTILE = (NP + MT - 1) / MT;   // 70

// Order-preserving fp32 -> uint32 (v1 > v2  <=>  key(v1) > key(v2))
__device__ __forceinline__ unsigned int fkey(float v) {
    unsigned int u = __float_as_uint(v);
    return (u & 0x80000000u) ? ~u : (u | 0x80000000u);
}

// ---------------- Kernel 1: per-pixel channel L2 normalize + NCHW->NHWC ----------------
__global__ __launch_bounds__(256) void normalize_kernel(
    const float* __restrict__ f1, const float* __restrict__ f2,
    float* __restrict__ fiN, float* __restrict__ frN, float* __restrict__ ssn)
{
    int t = blockIdx.x * 256 + threadIdx.x;
    const int perTensor = NITEM * HW;
    if (t >= 2 * perTensor) return;
    int which = t / perTensor;
    int p = t - which * perTensor;
    int n = p / HW;
    int pix = p - n * HW;
    const float* src = (which ? f2 : f1) + (size_t)n * C * HW + pix;
    float s = 0.f;
    #pragma unroll
    for (int c = 0; c < C; c++) {
        float v = src[c * HW];
        s = fmaf(v, v, s);
    }
    float norm = sqrtf(s);
    float scale = 1.0f / fmaxf(norm, 1e-12f);
    float* dst = (which ? frN : fiN) + (size_t)p * C;
    #pragma unroll
    for (int c = 0; c < C; c++) {
        dst[c] = src[c * HW] * scale;
    }
    if (which) ssn[p] = s * scale * scale;
}

// ---------------- Kernel 2: ref patch inverse norms ----------------
__global__ __launch_bounds__(256) void refnorm_kernel(
    const float* __restrict__ ssn, float* __restrict__ invn)
{
    int t = blockIdx.x * 256 + threadIdx.x;
    if (t >= NITEM * NP) return;
    int n = t / NP;
    int r = t - n * NP;
    int yr = r / HP, xr = r - yr * HP;
    const float* s = ssn + n * HW;
    float acc = 0.f;
    #pragma unroll
    for (int dy = 0; dy < 3; dy++)
        #pragma unroll
        for (int dx = 0; dx < 3; dx++)
            acc += s[(yr + dy) * W + (xr + dx)];
    invn[t] = 1.0f / (sqrtf(acc) + 1e-5f);
}

// ================= FACTORED PATH =================
// Kernel A: GEMM writing RAW pixel-corr P[q][p]; 128q x 256p tile, 8x16/thread.
// FMA:LDS = 128 FMA / 6 b128 -> 89% model ceiling. R18's tp=(t&15)*16 fragment
// base caused 8-way LDS conflicts (6.2e7 = 56% of cycles); fixed here with
// split p-fragments at tp4 + {0,64,128,192}, tp4=(t&15)*4 -> 2-way max (free).
// k-order 0..63 unchanged -> bit-identical P.
__global__ __launch_bounds__(256) void gemmP_kernel(
    const float* __restrict__ fiN, const float* __restrict__ frN,
    float* __restrict__ pmat, int ry0, int prows)
{
    __shared__ struct { float Aq[KC2][PADA]; float Bp[KC2][PADB]; } sm;  // 50.2 KB

    const int t = threadIdx.x;
    const int pt0 = blockIdx.x * TN;     // input-pixel col base (256-aligned)
    const int qt0 = blockIdx.y * TSQ;    // P-local q base (128-aligned)
    const int n = blockIdx.z;

    const float* fa = frN + (size_t)n * HW * C;  // q side (ref)
    const float* fb = fiN + (size_t)n * HW * C;  // p side (input)

    const int tq = (t >> 4) * 8;    // q fragment base (0..120)
    const int tp4 = (t & 15) * 4;   // p fragment base; chunks at +0,+64,+128,+192

    float acc[8][16];
    #pragma unroll
    for (int i = 0; i < 8; i++)
        #pragma unroll
        for (int j = 0; j < 16; j++) acc[i][j] = 0.f;

    // staging indices (round-invariant)
    int bpix = pt0 + t; if (bpix > HW - 1) bpix = HW - 1;            // Bp: 1 pixel/thread
    int arow = t >> 1;                                               // Aq: rows 0..127
    const int ach0 = (t & 1) * 16;                                   // ch half
    int apix = ry0 * W + qt0 + arow; if (apix > HW - 1) apix = HW - 1;

    #pragma unroll 1
    for (int kb = 0; kb < C; kb += KC2) {
        if (kb) __syncthreads();   // previous round's LDS reads complete
        {
            const float* pb = fb + (size_t)bpix * C + kb;
            #pragma unroll
            for (int u = 0; u < 8; u++) {
                float4 v = *(const float4*)(pb + 4 * u);
                sm.Bp[4 * u + 0][t] = v.x; sm.Bp[4 * u + 1][t] = v.y;
                sm.Bp[4 * u + 2][t] = v.z; sm.Bp[4 * u + 3][t] = v.w;
            }
            const float* qa = fa + (size_t)apix * C + kb + ach0;
            #pragma unroll
            for (int u = 0; u < 4; u++) {
                float4 v = *(const float4*)(qa + 4 * u);
                int cc = ach0 + 4 * u;
                sm.Aq[cc + 0][arow] = v.x; sm.Aq[cc + 1][arow] = v.y;
                sm.Aq[cc + 2][arow] = v.z; sm.Aq[cc + 3][arow] = v.w;
            }
        }
        __syncthreads();

        #pragma unroll 2
        for (int k = 0; k < KC2; k++) {
            float4 af0 = *(const float4*)&sm.Aq[k][tq];
            float4 af1 = *(const float4*)&sm.Aq[k][tq + 4];
            float4 bf0 = *(const float4*)&sm.Bp[k][tp4];
            float4 bf1 = *(const float4*)&sm.Bp[k][tp4 + 64];
            float4 bf2 = *(const float4*)&sm.Bp[k][tp4 + 128];
            float4 bf3 = *(const float4*)&sm.Bp[k][tp4 + 192];
            float av[8] = {af0.x, af0.y, af0.z, af0.w, af1.x, af1.y, af1.z, af1.w};
            float bw[16] = {bf0.x, bf0.y, bf0.z, bf0.w, bf1.x, bf1.y, bf1.z, bf1.w,
                            bf2.x, bf2.y, bf2.z, bf2.w, bf3.x, bf3.y, bf3.z, bf3.w};
            #pragma unroll
            for (int i = 0; i < 8; i++)
                #pragma unroll
                for (int j = 0; j < 16; j++)
                    acc[i][j] = fmaf(av[i], bw[j], acc[i][j]);
        }
    }

    // ---- direct register->global stores: 4 chunks of float4 per q-row, each
    // 16-lane group covers 256 B contiguous per chunk -> fully coalesced.
    float* pn = pmat + (size_t)n * prows * HW;
    #pragma unroll
    for (int i = 0; i < 8; i++) {
        int qL = qt0 + tq + i;
        if (qL < prows) {
            float* row = pn + (size_t)qL * HW + pt0 + tp4;
            *(float4*)(row + 0)   = make_float4(acc[i][0],  acc[i][1],  acc[i][2],  acc[i][3]);
            *(float4*)(row + 64)  = make_float4(acc[i][4],  acc[i][5],  acc[i][6],  acc[i][7]);
            *(float4*)(row + 128) = make_float4(acc[i][8],  acc[i][9],  acc[i][10], acc[i][11]);
            *(float4*)(row + 192) = make_float4(acc[i][12], acc[i][13], acc[i][14], acc[i][15]);
        }
    }
}

// Kernel B (R12-proven scalar form + atomic merge): 3x3 diagonal sum + norm
// scale + per-ry argmax, merged globally via packed-u64 atomicMax.
// key = (fkey(v) << 32) | ~idx  ->  max key == (max v, tie -> min idx).
__global__ __launch_bounds__(256) void pass2_kernel(
    const float* __restrict__ pmat, const float* __restrict__ invn,
    unsigned long long* __restrict__ best, int ry0, int prows)
{
    const int t = threadIdx.x;
    const int ryL = blockIdx.x;          // P-local ref patch-row
    const int ry = ry0 + ryL;            // global ref patch-row
    const int n = blockIdx.z;
    const int i = blockIdx.y * ITILE + t;
    if (i >= NP) return;

    const float* pn = pmat + (size_t)n * prows * HW;
    const float* inv = invn + (size_t)n * NP + ry * HP;
    const int rBase = ry * HP;

    int iy = i / HP, ix = i - iy * HP;
    int ppix = iy * W + ix;
    const float* b0 = pn + (size_t)(ryL * W) * HW + ppix;
    const float* b1 = b0 + (size_t)W * HW + W;
    const float* b2 = b1 + (size_t)W * HW + W;
    const size_t D = (size_t)HW + 1;     // diagonal stride (+1 row, +1 col)

    float bv = -INFINITY;
    int brx = 0;
    #pragma unroll 4
    for (int rx = 0; rx < HP; rx++) {
        size_t o = (size_t)rx * HW;
        float s0 = (b0[o] + b0[o + D]) + b0[o + 2 * D];
        float s1 = (b1[o] + b1[o + D]) + b1[o + 2 * D];
        float s2 = (b2[o] + b2[o + D]) + b2[o + 2 * D];
        float v = ((s0 + s1) + s2) * inv[rx];
        if (v > bv) { bv = v; brx = rx; }
    }
    unsigned long long key = ((unsigned long long)fkey(bv) << 32)
                           | (unsigned int)(~(unsigned int)(rBase + brx));
    atomicMax(&best[(size_t)n * NP + i], key);
}

// Expand to 9 shifted copies, channel-interleaved; decodes best[] inline.
__global__ __launch_bounds__(256) void expand_best_kernel(
    const unsigned long long* __restrict__ best, float* __restrict__ out)
{
    int t = blockIdx.x * 256 + threadIdx.x;
    const int total = NITEM * 18 * HW;
    if (t >= total) return;
    int x = t % W;
    int y = (t / W) % H;
    int chn = (t / HW) % 18;
    int n = t / (18 * HW);
    int k = chn >> 1;
    int b = chn & 1;          // 0 -> flow_h, 1 -> flow_w
    int is = k / 3, js = k - is * 3;
    int ys = y - is, xs = x - js;
    float val = 0.f;
    if (ys >= 0 && ys < HP && xs >= 0 && xs < HP) {
        int i = ys * HP + xs;
        unsigned long long key = best[(size_t)n * NP + i];
        int idx = (int)(~(unsigned int)key);
        int yr = idx / HP, xr = idx - yr * HP;
        val = b ? (float)(xr - xs) : (float)(yr - ys);
    }
    out[t] = val;
}

// ================= FALLBACK PATH (R4 direct, proven) =================
__global__ __launch_bounds__(256) void corr_kernel(
    const float* __restrict__ fiN, const float* __restrict__ frN,
    const float* __restrict__ invn,
    float* __restrict__ bestv, int* __restrict__ besti)
{
    __shared__ union SM {
        struct { float A[KC][LDP]; float B[KC][LDP]; } g;
        struct { float rv[MT][16]; int ri[MT][16]; } red;
    } sm;

    const int t = threadIdx.x;
    const int itile = blockIdx.x;
    const int seg = blockIdx.y;
    const int n = blockIdx.z;

    const float* fa = fiN + (size_t)n * HW * C;
    const float* fb = frN + (size_t)n * HW * C;
    const float* inv = invn + (size_t)n * NP;

    const int lrow = t >> 2;
    const int lc = (t & 3) * 4;

    int ia0 = itile * MT + lrow;      if (ia0 > NP - 1) ia0 = NP - 1;
    int ia1 = itile * MT + lrow + 64; if (ia1 > NP - 1) ia1 = NP - 1;
    const int ay0 = ia0 / HP, ax0 = ia0 - ay0 * HP;
    const int ay1 = ia1 / HP, ax1 = ia1 - ay1 * HP;
    const int aoff0 = (ay0 * W + ax0) * C;
    const int aoff1 = (ay1 * W + ax1) * C;

    const int tm4 = (t & 15) * 4;
    const int tn4 = (t >> 4) * 4;

    const int segStart = seg * SEGLEN;
    const int segEnd = (segStart + SEGLEN < NP) ? segStart + SEGLEN : NP;

    float bv[8];
    int bi[8];
    #pragma unroll
    for (int i = 0; i < 8; i++) { bv[i] = -INFINITY; bi[i] = 0; }

    for (int rt = segStart; rt < segEnd; rt += NT) {
        int ib0 = rt + lrow;      if (ib0 > NP - 1) ib0 = NP - 1;
        int ib1 = rt + lrow + 64; if (ib1 > NP - 1) ib1 = NP - 1;
        const int by0 = ib0 / HP, bx0 = ib0 - by0 * HP;
        const int by1 = ib1 / HP, bx1 = ib1 - by1 * HP;
        const int boff0 = (by0 * W + bx0) * C;
        const int boff1 = (by1 * W + bx1) * C;

        float acc[8][8];
        #pragma unroll
        for (int i = 0; i < 8; i++)
            #pragma unroll
            for (int j = 0; j < 8; j++) acc[i][j] = 0.f;

        float4 a0 = *(const float4*)(fa + aoff0 + lc);
        float4 a1 = *(const float4*)(fa + aoff1 + lc);
        float4 b0 = *(const float4*)(fb + boff0 + lc);
        float4 b1 = *(const float4*)(fb + boff1 + lc);

        #pragma unroll 1
        for (int ch = 0; ch < 36; ch++) {
            __syncthreads();
            sm.g.A[lc + 0][lrow] = a0.x; sm.g.A[lc + 1][lrow] = a0.y;
            sm.g.A[lc + 2][lrow] = a0.z; sm.g.A[lc + 3][lrow] = a0.w;
            sm.g.A[lc + 0][lrow + 64] = a1.x; sm.g.A[lc + 1][lrow + 64] = a1.y;
            sm.g.A[lc + 2][lrow + 64] = a1.z; sm.g.A[lc + 3][lrow + 64] = a1.w;
            sm.g.B[lc + 0][lrow] = b0.x; sm.g.B[lc + 1][lrow] = b0.y;
            sm.g.B[lc + 2][lrow] = b0.z; sm.g.B[lc + 3][lrow] = b0.w;
            sm.g.B[lc + 0][lrow + 64] = b1.x; sm.g.B[lc + 1][lrow + 64] = b1.y;
            sm.g.B[lc + 2][lrow + 64] = b1.z; sm.g.B[lc + 3][lrow + 64] = b1.w;
            __syncthreads();

            if (ch < 35) {
                const int chn = ch + 1;
                const int pp = chn >> 2;
                const int c0 = (chn & 3) << 4;
                const int dy = pp / 3, dx = pp - dy * 3;
                const int poff = (dy * W + dx) * C + c0 + lc;
                a0 = *(const float4*)(fa + aoff0 + poff);
                a1 = *(const float4*)(fa + aoff1 + poff);
                b0 = *(const float4*)(fb + boff0 + poff);
                b1 = *(const float4*)(fb + boff1 + poff);
            }

            #pragma unroll
            for (int k = 0; k < KC; k++) {
                float4 af0 = *(const float4*)&sm.g.A[k][tm4];
                float4 af1 = *(const float4*)&sm.g.A[k][tm4 + 64];
                float4 bf0 = *(const float4*)&sm.g.B[k][tn4];
                float4 bf1 = *(const float4*)&sm.g.B[k][tn4 + 64];
                float av[8] = {af0.x, af0.y, af0.z, af0.w, af1.x, af1.y, af1.z, af1.w};
                float bw[8] = {bf0.x, bf0.y, bf0.z, bf0.w, bf1.x, bf1.y, bf1.z, bf1.w};
                #pragma unroll
                for (int i = 0; i < 8; i++)
                    #pragma unroll
                    for (int j = 0; j < 8; j++)
                        acc[i][j] = fmaf(av[i], bw[j], acc[i][j]);
            }
        }

        #pragma unroll
        for (int j = 0; j < 8; j++) {
            int col = tn4 + ((j < 4) ? j : 60 + j);
            int r = rt + col;
            bool valid = (r < segEnd);
            float iv = inv[valid ? r : 0];
            #pragma unroll
            for (int i = 0; i < 8; i++) {
                float v = acc[i][j] * iv;
                if (valid && v > bv[i]) { bv[i] = v; bi[i] = r; }
            }
        }
    }

    __syncthreads();
    #pragma unroll
    for (int i = 0; i < 8; i++) {
        int row = tm4 + ((i < 4) ? i : 60 + i);
        sm.red.rv[row][t >> 4] = bv[i];
        sm.red.ri[row][t >> 4] = bi[i];
    }
    __syncthreads();
    if (t < MT) {
        float v = sm.red.rv[t][0];
        int idx = sm.red.ri[t][0];
        #pragma unroll
        for (int j = 1; j < 16; j++) {
            float v2 = sm.red.rv[t][j];
            int i2 = sm.red.ri[t][j];
            if (v2 > v || (v2 == v && i2 < idx)) { v = v2; idx = i2; }
        }
        int gi = itile * MT + t;
        if (gi < NP) {
            size_t o = ((size_t)n * NSEG + seg) * NP + gi;
            bestv[o] = v;
            besti[o] = idx;
        }
    }
}

__global__ __launch_bounds__(256) void reduce_flow_kernel(
    const float* __restrict__ bestv, const int* __restrict__ besti,
    float* __restrict__ flowh, float* __restrict__ floww)
{
    int t = blockIdx.x * 256 + threadIdx.x;
    if (t >= NITEM * NP) return;
    int n = t / NP;
    int i = t - n * NP;
    const float* bvp = bestv + (size_t)n * NSEG * NP;
    const int* bip = besti + (size_t)n * NSEG * NP;
    float v = bvp[i];
    int idx = bip[i];
    #pragma unroll
    for (int s = 1; s < NSEG; s++) {
        float v2 = bvp[s * NP + i];
        int i2 = bip[s * NP + i];
        if (v2 > v || (v2 == v && i2 < idx)) { v = v2; idx = i2; }
    }
    int yi = i / HP, xi = i - yi * HP;
    int yr = idx / HP, xr = idx - yr * HP;
    flowh[t] = (float)(yr - yi);
    floww[t] = (float)(xr - xi);
}

__global__ __launch_bounds__(256) void expand_kernel(
    const float* __restrict__ flowh, const float* __restrict__ floww,
    float* __restrict__ out)
{
    int t = blockIdx.x * 256 + threadIdx.x;
    const int total = NITEM * 18 * HW;
    if (t >= total) return;
    int x = t % W;
    int y = (t / W) % H;
    int chn = (t / HW) % 18;
    int n = t / (18 * HW);
    int k = chn >> 1;
    int b = chn & 1;
    int is = k / 3, js = k - is * 3;
    int ys = y - is, xs = x - js;
    float val = 0.f;
    if (ys >= 0 && ys < HP && xs >= 0 && xs < HP) {
        int src = n * NP + ys * HP + xs;
        val = b ? floww[src] : flowh[src];
    }
    out[t] = val;
}

// ---------------- Launch ----------------
extern "C" void kernel_launch(void* const* d_in, const int* in_sizes, int n_in,
                              void* d_out, int out_size, void* d_ws, size_t ws_size,
                              hipStream_t stream) {
    (void)in_sizes; (void)n_in; (void)out_size;
    const float* f1 = (const float*)d_in[0];
    const float* f2 = (const float*)d_in[1];
    float* ws = (float*)d_ws;

    // common carve
    float* fiN  = ws;                                  // 2*9216*64
    float* frN  = fiN + NITEM * HW * C;                // 2*9216*64
    float* ssn  = frN + NITEM * HW * C;                // 2*9216
    float* invn = ssn + NITEM * HW;                    // 2*8836
    float* after = invn + NITEM * NP;
    size_t afterOff = ((size_t)(after - ws) + 63) & ~(size_t)63;

    float* pmat = ws + afterOff;
    auto tier_fits = [&](int bry) {
        size_t prowsT = (size_t)(bry + 2) * W;
        size_t words = afterOff + (size_t)NITEM * prowsT * HW
                     + (size_t)NITEM * NP * 2 /* u64 best */;
        return ws_size >= words * sizeof(float);
    };

    int bry = 0;
    if (tier_fits(BRY_L)) bry = BRY_L;          // L3-resident band (proven best)
    else if (tier_fits(BRY_S)) bry = BRY_S;

    {
        int nthreads = 2 * NITEM * HW;
        normalize_kernel<<<(nthreads + 255) / 256, 256, 0, stream>>>(f1, f2, fiN, frN, ssn);
    }
    {
        int nthreads = NITEM * NP;
        refnorm_kernel<<<(nthreads + 255) / 256, 256, 0, stream>>>(ssn, invn);
    }

    if (bry > 0) {
        size_t prowsT = (size_t)(bry + 2) * W;
        unsigned long long* best =
            (unsigned long long*)(pmat + (size_t)NITEM * prowsT * HW);
        hipMemsetAsync(best, 0, (size_t)NITEM * NP * sizeof(unsigned long long), stream);

        for (int ry0 = 0; ry0 < HP; ry0 += bry) {
            int bryb = (HP - ry0 < bry) ? (HP - ry0) : bry;
            int prows_used = (bryb + 2) * W;
            int nqt = (prows_used + TSQ - 1) / TSQ;
            dim3 ga(NPT, nqt, NITEM);
            gemmP_kernel<<<ga, 256, 0, stream>>>(fiN, frN, pmat, ry0, prows_used);
            dim3 gb(bryb, NIT, NITEM);
            pass2_kernel<<<gb, 256, 0, stream>>>(pmat, invn, best, ry0, prows_used);
        }
        expand_best_kernel<<<(NITEM * 18 * HW + 255) / 256, 256, 0, stream>>>(
            best, (float*)d_out);
    } else {
        // direct fallback carve (fits ~10 MB)
        float* bestv = ws + afterOff;                       // 2*8*8836
        int*   besti = (int*)(bestv + NITEM * NSEG * NP);
        float* flowh = (float*)(besti + NITEM * NSEG * NP);
        float* floww = flowh + NITEM * NP;
        dim3 grid(NMTILE, NSEG, NITEM);
        corr_kernel<<<grid, 256, 0, stream>>>(fiN, frN, invn, bestv, besti);
        int nthreads = NITEM * NP;
        reduce_flow_kernel<<<(nthreads + 255) / 256, 256, 0, stream>>>(bestv, besti, flowh, floww);
        expand_kernel<<<(NITEM * 18 * HW + 255) / 256, 256, 0, stream>>>(flowh, floww, (float*)d_out);
    }
}

// Round 20
// 763.251 us; speedup vs baseline: 1.7759x; 1.0709x over previous
//
#include <hip/hip_runtime.h>
#include <math.h>

// Problem constants (N=2, C=64, H=96, W=96, PATCH=3)
static constexpr int NITEM = 2;
static constexpr int C = 64;
static constexpr int H = 96;
static constexpr int W = 96;
static constexpr int HW = H * W;         // 9216 pixels
static constexpr int HP = 94;            // H - 3 + 1
static constexpr int NP = HP * HP;       // 8836 patch positions

// ---- factored-path constants ----
// Band ladder: BRY24 (184 MB slab, 4 bands) measured best overall (R17, 805 us)
// -- gemmP halo saving slightly outweighs pass2's partial L3 spill. BRY18
// (142 MB, L3-resident) within noise (R16, 808 us). BRY47 regressed (R13).
static constexpr int BRY_M  = 24;                   // 4 bands, PROWS=2496
static constexpr int BRY_L  = 18;                   // 6 bands, PROWS=1920
static constexpr int BRY_S  = 8;                    // 12 bands, PROWS=960 (fallback)
static constexpr int TSP = 128;                     // tile edge
static constexpr int NPT = HW / TSP;                // 72 p-tiles (exact)
static constexpr int PAD = 132;                     // LDS row pad
static constexpr int ITILE = 256;                   // i's per pass2 block
static constexpr int NIT = (NP + ITILE - 1) / ITILE; // 35

// ---- fallback (R4 direct) constants ----
static constexpr int NSEG = 8;
static constexpr int SEGLEN = (NP + NSEG - 1) / NSEG; // 1105
static constexpr int MT = 128;
static constexpr int NT = 128;
static constexpr int KC = 16;
static constexpr int LDP = MT + 4;
static constexpr int NMTILE = (NP + MT - 1) / MT;   // 70

// Order-preserving fp32 -> uint32 (v1 > v2  <=>  key(v1) > key(v2))
__device__ __forceinline__ unsigned int fkey(float v) {
    unsigned int u = __float_as_uint(v);
    return (u & 0x80000000u) ? ~u : (u | 0x80000000u);
}

// ---------------- Kernel 1: per-pixel channel L2 normalize + NCHW->NHWC ----------------
__global__ __launch_bounds__(256) void normalize_kernel(
    const float* __restrict__ f1, const float* __restrict__ f2,
    float* __restrict__ fiN, float* __restrict__ frN, float* __restrict__ ssn)
{
    int t = blockIdx.x * 256 + threadIdx.x;
    const int perTensor = NITEM * HW;
    if (t >= 2 * perTensor) return;
    int which = t / perTensor;
    int p = t - which * perTensor;
    int n = p / HW;
    int pix = p - n * HW;
    const float* src = (which ? f2 : f1) + (size_t)n * C * HW + pix;
    float s = 0.f;
    #pragma unroll
    for (int c = 0; c < C; c++) {
        float v = src[c * HW];
        s = fmaf(v, v, s);
    }
    float norm = sqrtf(s);
    float scale = 1.0f / fmaxf(norm, 1e-12f);
    float* dst = (which ? frN : fiN) + (size_t)p * C;
    #pragma unroll
    for (int c = 0; c < C; c++) {
        dst[c] = src[c * HW] * scale;
    }
    if (which) ssn[p] = s * scale * scale;
}

// ---------------- Kernel 2: ref patch inverse norms ----------------
__global__ __launch_bounds__(256) void refnorm_kernel(
    const float* __restrict__ ssn, float* __restrict__ invn)
{
    int t = blockIdx.x * 256 + threadIdx.x;
    if (t >= NITEM * NP) return;
    int n = t / NP;
    int r = t - n * NP;
    int yr = r / HP, xr = r - yr * HP;
    const float* s = ssn + n * HW;
    float acc = 0.f;
    #pragma unroll
    for (int dy = 0; dy < 3; dy++)
        #pragma unroll
        for (int dx = 0; dx < 3; dx++)
            acc += s[(yr + dy) * W + (xr + dx)];
    invn[t] = 1.0f / (sqrtf(acc) + 1e-5f);
}

// ================= FACTORED PATH =================
// Kernel A (R10-proven 256-thread 8x8): GEMM writing RAW pixel-corr P[q][p].
// P[qL][p] = sum_c frN[ry0*W + qL][c] * fiN[p][c];  qL < prows.
// This structure is the measured plateau (~76 us/128-row-band dispatch):
// K-split (R7), 512-thr 4x8 (R11), and 8x16 tiles (R18/R19) all tied or
// regressed -- LDS-issue, occupancy, and barrier costs trade off to the
// same product.
__global__ __launch_bounds__(256) void gemmP_kernel(
    const float* __restrict__ fiN, const float* __restrict__ frN,
    float* __restrict__ pmat, int ry0, int prows)
{
    __shared__ struct { float Aq[C][PAD]; float Bp[C][PAD]; } sm;  // 67584 B

    const int t = threadIdx.x;
    const int pt0 = blockIdx.x * TSP;    // input-pixel col base (128-aligned)
    const int qt0 = blockIdx.y * TSP;    // P-local q base
    const int n = blockIdx.z;

    const float* fa = frN + (size_t)n * HW * C;  // q side (ref)
    const float* fb = fiN + (size_t)n * HW * C;  // p side (input)

    // ---- stage panels; channel map c0=(t&3)*4, cc=c0+16u -> LDS write 2-way max
    {
        const int lrow = t >> 2;
        const int c0 = (t & 3) * 4;
        #pragma unroll
        for (int rr = 0; rr < 2; rr++) {
            int m = lrow + rr * 64;
            int qpix = ry0 * W + qt0 + m; if (qpix > HW - 1) qpix = HW - 1;
            int ppix = pt0 + m;           if (ppix > HW - 1) ppix = HW - 1;
            const float* qa = fa + (size_t)qpix * C + c0;
            const float* pb = fb + (size_t)ppix * C + c0;
            #pragma unroll
            for (int u = 0; u < 4; u++) {
                float4 va = *(const float4*)(qa + 16 * u);
                float4 vb = *(const float4*)(pb + 16 * u);
                int cc = c0 + 16 * u;
                sm.Aq[cc + 0][m] = va.x; sm.Aq[cc + 1][m] = va.y;
                sm.Aq[cc + 2][m] = va.z; sm.Aq[cc + 3][m] = va.w;
                sm.Bp[cc + 0][m] = vb.x; sm.Bp[cc + 1][m] = vb.y;
                sm.Bp[cc + 2][m] = vb.z; sm.Bp[cc + 3][m] = vb.w;
            }
        }
    }
    __syncthreads();

    // ---- 128x128 GEMM, K=64. q slow across lanes (broadcast), p fast (coalesced stores).
    const int tmq = (t >> 4) * 4;   // q fragment base
    const int tnp = (t & 15) * 4;   // p fragment base
    float acc[8][8];
    #pragma unroll
    for (int i = 0; i < 8; i++)
        #pragma unroll
        for (int j = 0; j < 8; j++) acc[i][j] = 0.f;

    #pragma unroll 4
    for (int k = 0; k < C; k++) {
        float4 af0 = *(const float4*)&sm.Aq[k][tmq];
        float4 af1 = *(const float4*)&sm.Aq[k][tmq + 64];
        float4 bf0 = *(const float4*)&sm.Bp[k][tnp];
        float4 bf1 = *(const float4*)&sm.Bp[k][tnp + 64];
        float av[8] = {af0.x, af0.y, af0.z, af0.w, af1.x, af1.y, af1.z, af1.w};
        float bw[8] = {bf0.x, bf0.y, bf0.z, bf0.w, bf1.x, bf1.y, bf1.z, bf1.w};
        #pragma unroll
        for (int i = 0; i < 8; i++)
            #pragma unroll
            for (int j = 0; j < 8; j++)
                acc[i][j] = fmaf(av[i], bw[j], acc[i][j]);
    }

    // ---- direct register->global stores (two float4 per q-row), fully coalesced
    float* pn = pmat + (size_t)n * prows * HW;
    #pragma unroll
    for (int i = 0; i < 8; i++) {
        int qq = tmq + ((i < 4) ? i : 60 + i);
        int qL = qt0 + qq;
        if (qL < prows) {
            float* row = pn + (size_t)qL * HW + pt0;
            *(float4*)(row + tnp)      = make_float4(acc[i][0], acc[i][1], acc[i][2], acc[i][3]);
            *(float4*)(row + tnp + 64) = make_float4(acc[i][4], acc[i][5], acc[i][6], acc[i][7]);
        }
    }
}

// Kernel B (R12-proven scalar form + atomic merge): 3x3 diagonal sum + norm
// scale + per-ry argmax, merged globally via packed-u64 atomicMax.
// key = (fkey(v) << 32) | ~idx  ->  max key == (max v, tie -> min idx), which
// is exactly the reference's ascending strict-'>' scan semantics.
// term(dy,dx) = P[(ryL+dy)*W + rx + dx][ppix + dy*W + dx] -> offset rx*HW + dx*(HW+1).
__global__ __launch_bounds__(256) void pass2_kernel(
    const float* __restrict__ pmat, const float* __restrict__ invn,
    unsigned long long* __restrict__ best, int ry0, int prows)
{
    const int t = threadIdx.x;
    const int ryL = blockIdx.x;          // P-local ref patch-row
    const int ry = ry0 + ryL;            // global ref patch-row
    const int n = blockIdx.z;
    const int i = blockIdx.y * ITILE + t;
    if (i >= NP) return;

    const float* pn = pmat + (size_t)n * prows * HW;
    const float* inv = invn + (size_t)n * NP + ry * HP;
    const int rBase = ry * HP;

    int iy = i / HP, ix = i - iy * HP;
    int ppix = iy * W + ix;
    const float* b0 = pn + (size_t)(ryL * W) * HW + ppix;
    const float* b1 = b0 + (size_t)W * HW + W;
    const float* b2 = b1 + (size_t)W * HW + W;
    const size_t D = (size_t)HW + 1;     // diagonal stride (+1 row, +1 col)

    float bv = -INFINITY;
    int brx = 0;
    #pragma unroll 4
    for (int rx = 0; rx < HP; rx++) {
        size_t o = (size_t)rx * HW;
        float s0 = (b0[o] + b0[o + D]) + b0[o + 2 * D];
        float s1 = (b1[o] + b1[o + D]) + b1[o + 2 * D];
        float s2 = (b2[o] + b2[o + D]) + b2[o + 2 * D];
        float v = ((s0 + s1) + s2) * inv[rx];
        if (v > bv) { bv = v; brx = rx; }
    }
    unsigned long long key = ((unsigned long long)fkey(bv) << 32)
                           | (unsigned int)(~(unsigned int)(rBase + brx));
    atomicMax(&best[(size_t)n * NP + i], key);
}

// Expand to 9 shifted copies, channel-interleaved; decodes best[] inline.
__global__ __launch_bounds__(256) void expand_best_kernel(
    const unsigned long long* __restrict__ best, float* __restrict__ out)
{
    int t = blockIdx.x * 256 + threadIdx.x;
    const int total = NITEM * 18 * HW;
    if (t >= total) return;
    int x = t % W;
    int y = (t / W) % H;
    int chn = (t / HW) % 18;
    int n = t / (18 * HW);
    int k = chn >> 1;
    int b = chn & 1;          // 0 -> flow_h, 1 -> flow_w
    int is = k / 3, js = k - is * 3;
    int ys = y - is, xs = x - js;
    float val = 0.f;
    if (ys >= 0 && ys < HP && xs >= 0 && xs < HP) {
        int i = ys * HP + xs;
        unsigned long long key = best[(size_t)n * NP + i];
        int idx = (int)(~(unsigned int)key);
        int yr = idx / HP, xr = idx - yr * HP;
        val = b ? (float)(xr - xs) : (float)(yr - ys);
    }
    out[t] = val;
}

// ================= FALLBACK PATH (R4 direct, proven) =================
__global__ __launch_bounds__(256) void corr_kernel(
    const float* __restrict__ fiN, const float* __restrict__ frN,
    const float* __restrict__ invn,
    float* __restrict__ bestv, int* __restrict__ besti)
{
    __shared__ union SM {
        struct { float A[KC][LDP]; float B[KC][LDP]; } g;
        struct { float rv[MT][16]; int ri[MT][16]; } red;
    } sm;

    const int t = threadIdx.x;
    const int itile = blockIdx.x;
    const int seg = blockIdx.y;
    const int n = blockIdx.z;

    const float* fa = fiN + (size_t)n * HW * C;
    const float* fb = frN + (size_t)n * HW * C;
    const float* inv = invn + (size_t)n * NP;

    const int lrow = t >> 2;
    const int lc = (t & 3) * 4;

    int ia0 = itile * MT + lrow;      if (ia0 > NP - 1) ia0 = NP - 1;
    int ia1 = itile * MT + lrow + 64; if (ia1 > NP - 1) ia1 = NP - 1;
    const int ay0 = ia0 / HP, ax0 = ia0 - ay0 * HP;
    const int ay1 = ia1 / HP, ax1 = ia1 - ay1 * HP;
    const int aoff0 = (ay0 * W + ax0) * C;
    const int aoff1 = (ay1 * W + ax1) * C;

    const int tm4 = (t & 15) * 4;
    const int tn4 = (t >> 4) * 4;

    const int segStart = seg * SEGLEN;
    const int segEnd = (segStart + SEGLEN < NP) ? segStart + SEGLEN : NP;

    float bv[8];
    int bi[8];
    #pragma unroll
    for (int i = 0; i < 8; i++) { bv[i] = -INFINITY; bi[i] = 0; }

    for (int rt = segStart; rt < segEnd; rt += NT) {
        int ib0 = rt + lrow;      if (ib0 > NP - 1) ib0 = NP - 1;
        int ib1 = rt + lrow + 64; if (ib1 > NP - 1) ib1 = NP - 1;
        const int by0 = ib0 / HP, bx0 = ib0 - by0 * HP;
        const int by1 = ib1 / HP, bx1 = ib1 - by1 * HP;
        const int boff0 = (by0 * W + bx0) * C;
        const int boff1 = (by1 * W + bx1) * C;

        float acc[8][8];
        #pragma unroll
        for (int i = 0; i < 8; i++)
            #pragma unroll
            for (int j = 0; j < 8; j++) acc[i][j] = 0.f;

        float4 a0 = *(const float4*)(fa + aoff0 + lc);
        float4 a1 = *(const float4*)(fa + aoff1 + lc);
        float4 b0 = *(const float4*)(fb + boff0 + lc);
        float4 b1 = *(const float4*)(fb + boff1 + lc);

        #pragma unroll 1
        for (int ch = 0; ch < 36; ch++) {
            __syncthreads();
            sm.g.A[lc + 0][lrow] = a0.x; sm.g.A[lc + 1][lrow] = a0.y;
            sm.g.A[lc + 2][lrow] = a0.z; sm.g.A[lc + 3][lrow] = a0.w;
            sm.g.A[lc + 0][lrow + 64] = a1.x; sm.g.A[lc + 1][lrow + 64] = a1.y;
            sm.g.A[lc + 2][lrow + 64] = a1.z; sm.g.A[lc + 3][lrow + 64] = a1.w;
            sm.g.B[lc + 0][lrow] = b0.x; sm.g.B[lc + 1][lrow] = b0.y;
            sm.g.B[lc + 2][lrow] = b0.z; sm.g.B[lc + 3][lrow] = b0.w;
            sm.g.B[lc + 0][lrow + 64] = b1.x; sm.g.B[lc + 1][lrow + 64] = b1.y;
            sm.g.B[lc + 2][lrow + 64] = b1.z; sm.g.B[lc + 3][lrow + 64] = b1.w;
            __syncthreads();

            if (ch < 35) {
                const int chn = ch + 1;
                const int pp = chn >> 2;
                const int c0 = (chn & 3) << 4;
                const int dy = pp / 3, dx = pp - dy * 3;
                const int poff = (dy * W + dx) * C + c0 + lc;
                a0 = *(const float4*)(fa + aoff0 + poff);
                a1 = *(const float4*)(fa + aoff1 + poff);
                b0 = *(const float4*)(fb + boff0 + poff);
                b1 = *(const float4*)(fb + boff1 + poff);
            }

            #pragma unroll
            for (int k = 0; k < KC; k++) {
                float4 af0 = *(const float4*)&sm.g.A[k][tm4];
                float4 af1 = *(const float4*)&sm.g.A[k][tm4 + 64];
                float4 bf0 = *(const float4*)&sm.g.B[k][tn4];
                float4 bf1 = *(const float4*)&sm.g.B[k][tn4 + 64];
                float av[8] = {af0.x, af0.y, af0.z, af0.w, af1.x, af1.y, af1.z, af1.w};
                float bw[8] = {bf0.x, bf0.y, bf0.z, bf0.w, bf1.x, bf1.y, bf1.z, bf1.w};
                #pragma unroll
                for (int i = 0; i < 8; i++)
                    #pragma unroll
                    for (int j = 0; j < 8; j++)
                        acc[i][j] = fmaf(av[i], bw[j], acc[i][j]);
            }
        }

        #pragma unroll
        for (int j = 0; j < 8; j++) {
            int col = tn4 + ((j < 4) ? j : 60 + j);
            int r = rt + col;
            bool valid = (r < segEnd);
            float iv = inv[valid ? r : 0];
            #pragma unroll
            for (int i = 0; i < 8; i++) {
                float v = acc[i][j] * iv;
                if (valid && v > bv[i]) { bv[i] = v; bi[i] = r; }
            }
        }
    }

    __syncthreads();
    #pragma unroll
    for (int i = 0; i < 8; i++) {
        int row = tm4 + ((i < 4) ? i : 60 + i);
        sm.red.rv[row][t >> 4] = bv[i];
        sm.red.ri[row][t >> 4] = bi[i];
    }
    __syncthreads();
    if (t < MT) {
        float v = sm.red.rv[t][0];
        int idx = sm.red.ri[t][0];
        #pragma unroll
        for (int j = 1; j < 16; j++) {
            float v2 = sm.red.rv[t][j];
            int i2 = sm.red.ri[t][j];
            if (v2 > v || (v2 == v && i2 < idx)) { v = v2; idx = i2; }
        }
        int gi = itile * MT + t;
        if (gi < NP) {
            size_t o = ((size_t)n * NSEG + seg) * NP + gi;
            bestv[o] = v;
            besti[o] = idx;
        }
    }
}

__global__ __launch_bounds__(256) void reduce_flow_kernel(
    const float* __restrict__ bestv, const int* __restrict__ besti,
    float* __restrict__ flowh, float* __restrict__ floww)
{
    int t = blockIdx.x * 256 + threadIdx.x;
    if (t >= NITEM * NP) return;
    int n = t / NP;
    int i = t - n * NP;
    const float* bvp = bestv + (size_t)n * NSEG * NP;
    const int* bip = besti + (size_t)n * NSEG * NP;
    float v = bvp[i];
    int idx = bip[i];
    #pragma unroll
    for (int s = 1; s < NSEG; s++) {
        float v2 = bvp[s * NP + i];
        int i2 = bip[s * NP + i];
        if (v2 > v || (v2 == v && i2 < idx)) { v = v2; idx = i2; }
    }
    int yi = i / HP, xi = i - yi * HP;
    int yr = idx / HP, xr = idx - yr * HP;
    flowh[t] = (float)(yr - yi);
    floww[t] = (float)(xr - xi);
}

__global__ __launch_bounds__(256) void expand_kernel(
    const float* __restrict__ flowh, const float* __restrict__ floww,
    float* __restrict__ out)
{
    int t = blockIdx.x * 256 + threadIdx.x;
    const int total = NITEM * 18 * HW;
    if (t >= total) return;
    int x = t % W;
    int y = (t / W) % H;
    int chn = (t / HW) % 18;
    int n = t / (18 * HW);
    int k = chn >> 1;
    int b = chn & 1;
    int is = k / 3, js = k - is * 3;
    int ys = y - is, xs = x - js;
    float val = 0.f;
    if (ys >= 0 && ys < HP && xs >= 0 && xs < HP) {
        int src = n * NP + ys * HP + xs;
        val = b ? floww[src] : flowh[src];
    }
    out[t] = val;
}

// ---------------- Launch ----------------
extern "C" void kernel_launch(void* const* d_in, const int* in_sizes, int n_in,
                              void* d_out, int out_size, void* d_ws, size_t ws_size,
                              hipStream_t stream) {
    (void)in_sizes; (void)n_in; (void)out_size;
    const float* f1 = (const float*)d_in[0];
    const float* f2 = (const float*)d_in[1];
    float* ws = (float*)d_ws;

    // common carve
    float* fiN  = ws;                                  // 2*9216*64
    float* frN  = fiN + NITEM * HW * C;                // 2*9216*64
    float* ssn  = frN + NITEM * HW * C;                // 2*9216
    float* invn = ssn + NITEM * HW;                    // 2*8836
    float* after = invn + NITEM * NP;
    size_t afterOff = ((size_t)(after - ws) + 63) & ~(size_t)63;

    float* pmat = ws + afterOff;
    auto tier_fits = [&](int bry) {
        size_t prowsT = (size_t)(bry + 2) * W;
        size_t words = afterOff + (size_t)NITEM * prowsT * HW
                     + (size_t)NITEM * NP * 2 /* u64 best */;
        return ws_size >= words * sizeof(float);
    };

    int bry = 0;
    if (tier_fits(BRY_M)) bry = BRY_M;          // measured best (R17, 805 us)
    else if (tier_fits(BRY_L)) bry = BRY_L;     // L3-resident (R16, 808 us)
    else if (tier_fits(BRY_S)) bry = BRY_S;

    {
        int nthreads = 2 * NITEM * HW;
        normalize_kernel<<<(nthreads + 255) / 256, 256, 0, stream>>>(f1, f2, fiN, frN, ssn);
    }
    {
        int nthreads = NITEM * NP;
        refnorm_kernel<<<(nthreads + 255) / 256, 256, 0, stream>>>(ssn, invn);
    }

    if (bry > 0) {
        size_t prowsT = (size_t)(bry + 2) * W;
        unsigned long long* best =
            (unsigned long long*)(pmat + (size_t)NITEM * prowsT * HW);
        hipMemsetAsync(best, 0, (size_t)NITEM * NP * sizeof(unsigned long long), stream);

        for (int ry0 = 0; ry0 < HP; ry0 += bry) {
            int bryb = (HP - ry0 < bry) ? (HP - ry0) : bry;
            int prows_used = (bryb + 2) * W;
            int nqt = (prows_used + TSP - 1) / TSP;
            dim3 ga(NPT, nqt, NITEM);
            gemmP_kernel<<<ga, 256, 0, stream>>>(fiN, frN, pmat, ry0, prows_used);
            dim3 gb(bryb, NIT, NITEM);
            pass2_kernel<<<gb, 256, 0, stream>>>(pmat, invn, best, ry0, prows_used);
        }
        expand_best_kernel<<<(NITEM * 18 * HW + 255) / 256, 256, 0, stream>>>(
            best, (float*)d_out);
    } else {
        // direct fallback carve (fits ~10 MB)
        float* bestv = ws + afterOff;                       // 2*8*8836
        int*   besti = (int*)(bestv + NITEM * NSEG * NP);
        float* flowh = (float*)(besti + NITEM * NSEG * NP);
        float* floww = flowh + NITEM * NP;
        dim3 grid(NMTILE, NSEG, NITEM);
        corr_kernel<<<grid, 256, 0, stream>>>(fiN, frN, invn, bestv, besti);
        int nthreads = NITEM * NP;
        reduce_flow_kernel<<<(nthreads + 255) / 256, 256, 0, stream>>>(bestv, besti, flowh, floww);
        expand_kernel<<<(NITEM * 18 * HW + 255) / 256, 256, 0, stream>>>(flowh, floww, (float*)d_out);
    }
}